// Round 7
// baseline (2066.326 us; speedup 1.0000x reference)
//
#include <hip/hip_runtime.h>
#include <hip/hip_bf16.h>

constexpr int B_ = 8, N_ = 2048, K_ = 20;
constexpr float EPS_ = 1e-5f;

typedef __attribute__((ext_vector_type(8))) short short8;
typedef __attribute__((ext_vector_type(4))) float f32x4;

__device__ __forceinline__ unsigned short f2bf(float f) {
  unsigned u = __float_as_uint(f);
  unsigned r = (u + 0x7FFFu + ((u >> 16) & 1u)) >> 16;
  return (unsigned short)r;
}
__device__ __forceinline__ float bf2f(unsigned short h) {
  return __uint_as_float(((unsigned)h) << 16);
}

// ---- weight area offsets (in floats) ----
constexpr int OW1T = 0;                    // W1^T  [512][256]
constexpr int OWST = OW1T + 512 * 256;     // Ws^T  [512][256]
constexpr int OW2T = OWST + 512 * 256;     // W2^T  [256][256]
constexpr int OWQT = OW2T + 256 * 256;     // wq^T  [256][64]
constexpr int OWKT = OWQT + 256 * 64;
constexpr int OWVT = OWKT + 256 * 64;
constexpr int OWUT = OWVT + 256 * 64;
constexpr int OWRT = OWUT + 256 * 64;      // wr^T  [256][128]
constexpr int OWET = OWRT + 256 * 128;     // we^T  [o][co] 64x128
// bf16 split tables (repurposing the old f32 OWTC/OAW1 float budget):
constexpr int OWTH = OWET + 64 * 128;      // wt^T hi  ushort[128][256] (16384 fl)
constexpr int OWTL = OWTH + 16384;         // wt^T lo  ushort[128][256]
constexpr int OAW1H = OWTL + 16384;        // am_w1 hi ushort[256][64]  (8192 fl)
constexpr int OAW1L = OAW1H + 8192;        // am_w1 lo ushort[256][64]
constexpr int OPW1 = OAW1L + 8192;         // pm_w1 [ph][3]
constexpr int OPW2 = OPW1 + 64 * 3;        // pm_w2 [o][c] 64x64
constexpr int OB1  = OPW2 + 64 * 64;       // mv_b1 [256]
constexpr int OBS2 = OB1 + 256;            // mv_bs + mv_b2 [256]
constexpr int OBQ  = OBS2 + 256;
constexpr int OBK  = OBQ + 64;
constexpr int OBV  = OBK + 64;
constexpr int OBU  = OBV + 64;
constexpr int OBR  = OBU + 64;             // [128]
constexpr int OBE  = OBR + 128;            // [128]
constexpr int OPB1 = OBE + 128;            // [64]
constexpr int OPSC = OPB1 + 64;
constexpr int OPSH = OPSC + 64;
constexpr int OPB2 = OPSH + 64;
constexpr int OASC = OPB2 + 64;            // [256]
constexpr int OASH = OASC + 256;
constexpr int OAB1 = OASH + 256;
constexpr int OABT = OAB1 + 256;           // [64]

// ---- workspace byte offsets (28 MiB total) ----
constexpr size_t OFFB_WF   = 0;
constexpr size_t OFFB_IDX  = (size_t)2 << 20;
constexpr size_t OFFB_Q    = (size_t)4 << 20;   // [b][n][64]
constexpr size_t OFFB_K    = (size_t)8 << 20;   // [b][n][64]
constexpr size_t OFFB_U    = (size_t)12 << 20;  // [b][n][64]
constexpr size_t OFFB_V    = (size_t)16 << 20;  // [b][n][64]
constexpr size_t OFFB_IDEN = (size_t)20 << 20;  // [b][n][128]

struct InPtrs { const float* p[38]; };

// ------------------------------------------------------------------
// Weight prep: transposes + BN folds + bf16 hi/lo splits
// ------------------------------------------------------------------
__global__ __launch_bounds__(256) void k_prep(InPtrs in, float* __restrict__ wf) {
  const int tid = blockIdx.x * 256 + threadIdx.x;
  const int nth = gridDim.x * 256;
  const float *mv_w1 = in.p[4], *mv_b1 = in.p[5], *mv_w2 = in.p[6], *mv_b2 = in.p[7],
              *mv_ws = in.p[8], *mv_bs = in.p[9], *wk = in.p[10], *bk = in.p[11],
              *wq = in.p[12], *bq = in.p[13], *wv = in.p[14], *bv = in.p[15],
              *wu = in.p[16], *bu = in.p[17], *pm_w1 = in.p[18], *pm_b1 = in.p[19],
              *pm_g = in.p[20], *pm_be = in.p[21], *pm_m = in.p[22], *pm_v = in.p[23],
              *pm_w2 = in.p[24], *pm_b2 = in.p[25], *am_w1 = in.p[26], *am_b1 = in.p[27],
              *am_g = in.p[28], *am_be = in.p[29], *am_m = in.p[30], *am_v = in.p[31],
              *am_wt = in.p[32], *am_bt = in.p[33], *we = in.p[34], *be = in.p[35],
              *wr = in.p[36], *br = in.p[37];

  for (int i = tid; i < 512 * 256; i += nth) { int c = i >> 8, m = i & 255; wf[OW1T + i] = mv_w1[m * 512 + c]; }
  for (int i = tid; i < 512 * 256; i += nth) { int c = i >> 8, m = i & 255; wf[OWST + i] = mv_ws[m * 512 + c]; }
  for (int i = tid; i < 256 * 256; i += nth) { int c = i >> 8, m = i & 255; wf[OW2T + i] = mv_w2[m * 256 + c]; }
  for (int i = tid; i < 256 * 64; i += nth) { int c = i >> 6, m = i & 63; wf[OWQT + i] = wq[m * 256 + c]; }
  for (int i = tid; i < 256 * 64; i += nth) { int c = i >> 6, m = i & 63; wf[OWKT + i] = wk[m * 256 + c]; }
  for (int i = tid; i < 256 * 64; i += nth) { int c = i >> 6, m = i & 63; wf[OWVT + i] = wv[m * 256 + c]; }
  for (int i = tid; i < 256 * 64; i += nth) { int c = i >> 6, m = i & 63; wf[OWUT + i] = wu[m * 256 + c]; }
  for (int i = tid; i < 256 * 128; i += nth) { int c = i >> 7, m = i & 127; wf[OWRT + i] = wr[m * 256 + c]; }
  for (int i = tid; i < 64 * 128; i += nth) { int o = i >> 7, co = i & 127; wf[OWET + i] = we[co * 64 + o]; }
  // bf16 splits: am_wt^T [orr][c], am_w1 native [c(256)][d(64)]
  {
    unsigned short* wth = (unsigned short*)(wf + OWTH);
    unsigned short* wtl = (unsigned short*)(wf + OWTL);
    for (int i = tid; i < 128 * 256; i += nth) {
      int orr = i >> 8, c = i & 255;
      float w = am_wt[c * 128 + orr];
      unsigned short h = f2bf(w);
      wth[i] = h;
      wtl[i] = f2bf(w - bf2f(h));
    }
    unsigned short* a1h = (unsigned short*)(wf + OAW1H);
    unsigned short* a1l = (unsigned short*)(wf + OAW1L);
    for (int i = tid; i < 256 * 64; i += nth) {
      float w = am_w1[i];
      unsigned short h = f2bf(w);
      a1h[i] = h;
      a1l[i] = f2bf(w - bf2f(h));
    }
  }
  for (int i = tid; i < 192; i += nth) wf[OPW1 + i] = pm_w1[i];
  for (int i = tid; i < 4096; i += nth) wf[OPW2 + i] = pm_w2[i];
  for (int i = tid; i < 256; i += nth) {
    wf[OB1 + i] = mv_b1[i];
    wf[OBS2 + i] = mv_bs[i] + mv_b2[i];
    float sc = am_g[i] / sqrtf(am_v[i] + EPS_);
    wf[OASC + i] = sc;
    wf[OASH + i] = am_be[i] - am_m[i] * sc;
    wf[OAB1 + i] = am_b1[i];
  }
  for (int i = tid; i < 64; i += nth) {
    wf[OBQ + i] = bq[i]; wf[OBK + i] = bk[i];
    wf[OBV + i] = bv[i]; wf[OBU + i] = bu[i];
    wf[OABT + i] = am_bt[i]; wf[OPB1 + i] = pm_b1[i]; wf[OPB2 + i] = pm_b2[i];
    float sc = pm_g[i] / sqrtf(pm_v[i] + EPS_);
    wf[OPSC + i] = sc;
    wf[OPSH + i] = pm_be[i] - pm_m[i] * sc;
  }
  for (int i = tid; i < 128; i += nth) { wf[OBR + i] = br[i]; wf[OBE + i] = be[i]; }
}

// ------------------------------------------------------------------
// Fused mv-MLP + v/iden projections. Outputs transposed: [b][n][ch].
// ------------------------------------------------------------------
__global__ __launch_bounds__(256) void k_mv(const float* __restrict__ wf,
                                            const float* __restrict__ keyf,
                                            const float* __restrict__ qryf,
                                            float* __restrict__ vout,
                                            float* __restrict__ idenout) {
  const int b = blockIdx.y;
  const int n0 = blockIdx.x * 16;
  __shared__ float hidL[256][16];
  __shared__ float valL[256][16];
  __shared__ float wsL[16][64];
  __shared__ float xsL[16][16];
  const int tid = threadIdx.x;
  const int tn = tid & 15, tm = tid >> 4;

  for (int ms = 0; ms < 4; ++ms) {
    float acc[4] = {};
    for (int kt = 0; kt < 512; kt += 16) {
      for (int i = tid; i < 1024; i += 256) {
        int kk = i >> 6, col = i & 63;
        wsL[kk][col] = wf[OW1T + (size_t)(kt + kk) * 256 + ms * 64 + col];
      }
      {
        int kk = tid >> 4, col = tid & 15;
        int c = kt + kk;
        const float* s = (c < 256) ? keyf : qryf;
        xsL[kk][col] = s[((size_t)b * 256 + (c & 255)) * N_ + n0 + col];
      }
      __syncthreads();
#pragma unroll
      for (int kk = 0; kk < 16; ++kk) {
        float x = xsL[kk][tn];
        float4 w4 = *(const float4*)&wsL[kk][tm * 4];
        acc[0] += w4.x * x; acc[1] += w4.y * x; acc[2] += w4.z * x; acc[3] += w4.w * x;
      }
      __syncthreads();
    }
#pragma unroll
    for (int i = 0; i < 4; ++i)
      hidL[ms * 64 + tm * 4 + i][tn] = fmaxf(acc[i] + wf[OB1 + ms * 64 + tm * 4 + i], 0.f);
  }
  __syncthreads();

  for (int ms = 0; ms < 4; ++ms) {
    float acc[4] = {};
    for (int kt = 0; kt < 512; kt += 16) {
      for (int i = tid; i < 1024; i += 256) {
        int kk = i >> 6, col = i & 63;
        wsL[kk][col] = wf[OWST + (size_t)(kt + kk) * 256 + ms * 64 + col];
      }
      {
        int kk = tid >> 4, col = tid & 15;
        int c = kt + kk;
        const float* s = (c < 256) ? keyf : qryf;
        xsL[kk][col] = s[((size_t)b * 256 + (c & 255)) * N_ + n0 + col];
      }
      __syncthreads();
#pragma unroll
      for (int kk = 0; kk < 16; ++kk) {
        float x = xsL[kk][tn];
        float4 w4 = *(const float4*)&wsL[kk][tm * 4];
        acc[0] += w4.x * x; acc[1] += w4.y * x; acc[2] += w4.z * x; acc[3] += w4.w * x;
      }
      __syncthreads();
    }
    for (int kt = 0; kt < 256; kt += 16) {
      for (int i = tid; i < 1024; i += 256) {
        int kk = i >> 6, col = i & 63;
        wsL[kk][col] = wf[OW2T + (size_t)(kt + kk) * 256 + ms * 64 + col];
      }
      __syncthreads();
#pragma unroll
      for (int kk = 0; kk < 16; ++kk) {
        float x = hidL[kt + kk][tn];
        float4 w4 = *(const float4*)&wsL[kk][tm * 4];
        acc[0] += w4.x * x; acc[1] += w4.y * x; acc[2] += w4.z * x; acc[3] += w4.w * x;
      }
      __syncthreads();
    }
#pragma unroll
    for (int i = 0; i < 4; ++i)
      valL[ms * 64 + tm * 4 + i][tn] = acc[i] + wf[OBS2 + ms * 64 + tm * 4 + i];
  }
  __syncthreads();

  {
    float acc[4] = {};
    for (int kt = 0; kt < 256; kt += 16) {
      for (int i = tid; i < 1024; i += 256) {
        int kk = i >> 6, col = i & 63;
        wsL[kk][col] = wf[OWVT + (size_t)(kt + kk) * 64 + col];
      }
      __syncthreads();
#pragma unroll
      for (int kk = 0; kk < 16; ++kk) {
        float x = valL[kt + kk][tn];
        float4 w4 = *(const float4*)&wsL[kk][tm * 4];
        acc[0] += w4.x * x; acc[1] += w4.y * x; acc[2] += w4.z * x; acc[3] += w4.w * x;
      }
      __syncthreads();
    }
    *(float4*)(vout + ((size_t)b * N_ + n0 + tn) * 64 + tm * 4) =
        make_float4(acc[0] + wf[OBV + tm * 4], acc[1] + wf[OBV + tm * 4 + 1],
                    acc[2] + wf[OBV + tm * 4 + 2], acc[3] + wf[OBV + tm * 4 + 3]);
  }
  for (int ms = 0; ms < 2; ++ms) {
    float acc[4] = {};
    for (int kt = 0; kt < 256; kt += 16) {
      for (int i = tid; i < 1024; i += 256) {
        int kk = i >> 6, col = i & 63;
        wsL[kk][col] = wf[OWRT + (size_t)(kt + kk) * 128 + ms * 64 + col];
      }
      __syncthreads();
#pragma unroll
      for (int kk = 0; kk < 16; ++kk) {
        float x = valL[kt + kk][tn];
        float4 w4 = *(const float4*)&wsL[kk][tm * 4];
        acc[0] += w4.x * x; acc[1] += w4.y * x; acc[2] += w4.z * x; acc[3] += w4.w * x;
      }
      __syncthreads();
    }
    int m = ms * 64 + tm * 4;
    *(float4*)(idenout + ((size_t)b * N_ + n0 + tn) * 128 + m) =
        make_float4(acc[0] + wf[OBR + m], acc[1] + wf[OBR + m + 1],
                    acc[2] + wf[OBR + m + 2], acc[3] + wf[OBR + m + 3]);
  }
}

// ------------------------------------------------------------------
// q/k/u projections, one launch; outputs transposed [b][n][64].
// ------------------------------------------------------------------
struct Gx { const float* x0; const float* x1; const float* x2;
            float* o0; float* o1; float* o2; };

__global__ __launch_bounds__(256) void k_gemm64x3(const float* __restrict__ wf, Gx g) {
  const int b = blockIdx.z;
  const int n0 = blockIdx.x * 64;
  const int y = blockIdx.y;
  const int wsel = (y == 2) ? 3 : y;
  const float* Wt = wf + OWQT + wsel * (256 * 64);
  const float* bias = wf + OBQ + wsel * 64;
  const float* x = (y == 0) ? g.x0 : (y == 1) ? g.x1 : g.x2;
  float* out = (y == 0) ? g.o0 : (y == 1) ? g.o1 : g.o2;
  __shared__ float ws_[16][64];
  __shared__ float xs_[16][64];
  const int tid = threadIdx.x, tm = tid & 15, tn = tid >> 4;
  float acc[4][4] = {};
  for (int kt = 0; kt < 256; kt += 16) {
    for (int i = tid; i < 1024; i += 256) {
      int kk = i >> 6, col = i & 63;
      ws_[kk][col] = Wt[(size_t)(kt + kk) * 64 + col];
      xs_[kk][col] = x[((size_t)b * 256 + kt + kk) * N_ + n0 + col];
    }
    __syncthreads();
#pragma unroll
    for (int kk = 0; kk < 16; ++kk) {
      float4 x4 = *(const float4*)&xs_[kk][tn * 4];
      float4 w4 = *(const float4*)&ws_[kk][tm * 4];
      float wv[4] = {w4.x, w4.y, w4.z, w4.w};
      float xv[4] = {x4.x, x4.y, x4.z, x4.w};
#pragma unroll
      for (int i = 0; i < 4; ++i)
#pragma unroll
        for (int j = 0; j < 4; ++j) acc[i][j] += wv[i] * xv[j];
    }
    __syncthreads();
  }
#pragma unroll
  for (int j = 0; j < 4; ++j) {
    *(float4*)(out + ((size_t)b * N_ + n0 + tn * 4 + j) * 64 + tm * 4) =
        make_float4(acc[0][j] + bias[tm * 4], acc[1][j] + bias[tm * 4 + 1],
                    acc[2][j] + bias[tm * 4 + 2], acc[3][j] + bias[tm * 4 + 3]);
  }
}

// ------------------------------------------------------------------
// Self-KNN, register-resident, 1 barrier per round.
// ------------------------------------------------------------------
__global__ __launch_bounds__(256, 4) void k_knn(const float* __restrict__ pos,
                                                int* __restrict__ idxout) {
  const int b = blockIdx.x >> 11, n = blockIdx.x & 2047;
  __shared__ double redd[2][4];
  __shared__ int redi[2][4];
  const int tid = threadIdx.x;
  const float* pb = pos + (size_t)b * 3 * N_;
  const double xq = pb[n], yq = pb[N_ + n], zq = pb[2 * N_ + n];
  const double sq = xq * xq + yq * yq + zq * zq;
  double d2[8];
#pragma unroll
  for (int s = 0; s < 8; ++s) {
    int i = tid + s * 256;
    double x = pb[i], y = pb[N_ + i], z = pb[2 * N_ + i];
    double psq = x * x + y * y + z * z;
    double dot = xq * x + yq * y + zq * z;
    d2[s] = (sq + psq) - 2.0 * dot;
  }
  const int lane = tid & 63, wv = tid >> 6;
  for (int r = 0; r < K_; ++r) {
    double bd = d2[0];
    int bi = tid;
#pragma unroll
    for (int s = 1; s < 8; ++s)
      if (d2[s] < bd) { bd = d2[s]; bi = tid + s * 256; }
#pragma unroll
    for (int off = 32; off; off >>= 1) {
      double od = __shfl_down(bd, off);
      int oi = __shfl_down(bi, off);
      if (od < bd || (od == bd && oi < bi)) { bd = od; bi = oi; }
    }
    int ph = r & 1;
    if (lane == 0) { redd[ph][wv] = bd; redi[ph][wv] = bi; }
    __syncthreads();
    double md = redd[ph][0];
    int mi = redi[ph][0];
#pragma unroll
    for (int w = 1; w < 4; ++w)
      if (redd[ph][w] < md || (redd[ph][w] == md && redi[ph][w] < mi)) { md = redd[ph][w]; mi = redi[ph][w]; }
    if (tid == 0) idxout[((size_t)b * N_ + n) * K_ + r] = mi;
    if ((mi & 255) == tid) d2[mi >> 8] = __builtin_inf();
  }
}

// ------------------------------------------------------------------
// Fused attention tail v4: P4/P5 on MFMA via split-bf16 (bf16x3).
// LDS float map (total 10536 fl = 42.1 KB -> 3 blocks/CU):
//   0    : sS  [20][65] f32        (dead after conversion; lg overlays 0..2580)
//   1300 : t1s [20][64] f32        (dead after P3)
//   2580 : sVal[20][65] f32
//   3880 : sSh ushort[32][72]      (1152 fl)
//   5032 : sSl ushort[32][72]
//   6184 : sHh ushort[16][264]     (2112 fl)
//   8296 : sHl ushort[16][264]
//   10408: aggs[128]
// ------------------------------------------------------------------
__global__ __launch_bounds__(256, 3) void k_attn(
    const float* __restrict__ wf,
    const float* __restrict__ qb, const float* __restrict__ kb,
    const float* __restrict__ vb, const float* __restrict__ ub,
    const float* __restrict__ idenb, const int* __restrict__ idxb,
    const float* __restrict__ pos, float* __restrict__ out) {
  const int b = blockIdx.x >> 11, n = blockIdx.x & 2047;
  const int tid = threadIdx.x;
  __shared__ __align__(16) float smem[10536];
  float* sS   = smem;
  float* t1s  = smem + 1300;
  float* lg   = smem;                 // [20][129] overlays sS+t1s
  float* sVal = smem + 2580;
  unsigned short* sSh = (unsigned short*)(smem + 3880);
  unsigned short* sSl = (unsigned short*)(smem + 5032);
  unsigned short* sHh = (unsigned short*)(smem + 6184);
  unsigned short* sHl = (unsigned short*)(smem + 8296);
  float* aggs = smem + 10408;
  __shared__ int idxs[20];
  __shared__ float prx[20], pry[20], prz[20];

  if (tid < 20) idxs[tid] = idxb[((size_t)b * N_ + n) * K_ + tid] & 2047;
  __syncthreads();

  const int o64 = tid & 63, kslot = tid >> 6, kk0 = kslot * 5;
  const int wave = tid >> 6, lane = tid & 63;
  const int l15 = lane & 15, quad = lane >> 4;

  // P1: coalesced gathers, fold q/u terms
  {
    size_t rowq = ((size_t)b * N_ + n) * 64;
    float qvo = qb[rowq + o64];
    float ufo = ub[rowq + o64];
#pragma unroll
    for (int t = 0; t < 5; ++t) {
      int kk = kk0 + t;
      int j = idxs[kk];
      size_t rowj = ((size_t)b * N_ + j) * 64;
      float kvv = kb[rowj + o64], vvv = vb[rowj + o64], uvv = ub[rowj + o64];
      float ur = ufo - uvv;
      sS[kk * 65 + o64] = (qvo - kvv) + ur;
      sVal[kk * 65 + o64] = vvv + ur;
    }
    if (tid < 20) {
      int j = idxs[tid];
      const float* pp = pos + (size_t)b * 3 * N_;
      prx[tid] = pp[n] - pp[j];
      pry[tid] = pp[N_ + n] - pp[N_ + j];
      prz[tid] = pp[2 * N_ + n] - pp[2 * N_ + j];
    }
  }
  __syncthreads();

  // P2: pos-MLP layer1 + BN + relu -> t1s[kk][ph]
  {
    int ph = o64;
    float w0 = wf[OPW1 + ph * 3], w1 = wf[OPW1 + ph * 3 + 1], w2 = wf[OPW1 + ph * 3 + 2];
    float pb1 = wf[OPB1 + ph], sc = wf[OPSC + ph], sh = wf[OPSH + ph];
#pragma unroll
    for (int t = 0; t < 5; ++t) {
      int kk = kk0 + t;
      float u = pb1 + w0 * prx[kk] + w1 * pry[kk] + w2 * prz[kk];
      t1s[kk * 64 + ph] = fmaxf(u * sc + sh, 0.f);
    }
  }
  __syncthreads();

  // P3: pos-MLP layer2 in registers, fold into s/val
  {
    float pes[5];
    float pb2 = wf[OPB2 + o64];
#pragma unroll
    for (int t = 0; t < 5; ++t) pes[t] = pb2;
    const float* w = wf + OPW2 + o64 * 64;
#pragma unroll 4
    for (int c4 = 0; c4 < 16; ++c4) {
      float4 w4 = *(const float4*)(w + c4 * 4);
#pragma unroll
      for (int t = 0; t < 5; ++t) {
        float4 tv = *(const float4*)(t1s + (kk0 + t) * 64 + c4 * 4);
        pes[t] += w4.x * tv.x + w4.y * tv.y + w4.z * tv.z + w4.w * tv.w;
      }
    }
#pragma unroll
    for (int t = 0; t < 5; ++t) {
      int idx = (kk0 + t) * 65 + o64;
      sS[idx] += pes[t];
      sVal[idx] += pes[t];
    }
  }
  __syncthreads();

  // Conversion: s -> bf16 hi/lo [kk][72]
  {
#pragma unroll
    for (int t = 0; t < 5; ++t) {
      int kk = kk0 + t;
      float v = sS[kk * 65 + o64];
      unsigned short h = f2bf(v);
      sSh[kk * 72 + o64] = h;
      sSl[kk * 72 + o64] = f2bf(v - bf2f(h));
    }
  }
  __syncthreads();

  const unsigned short* aw1h = (const unsigned short*)(wf + OAW1H);
  const unsigned short* aw1l = (const unsigned short*)(wf + OAW1L);
  const unsigned short* wth  = (const unsigned short*)(wf + OWTH);
  const unsigned short* wtl  = (const unsigned short*)(wf + OWTL);

  for (int nt = 0; nt < 2; ++nt) {
    // P4: h[256][16-cols] = am_w1 @ s  (split-bf16 MFMA), BN+relu, split-store
#pragma unroll
    for (int mt = 0; mt < 4; ++mt) {
      int m16 = (wave * 4 + mt) * 16;
      f32x4 acc = {0.f, 0.f, 0.f, 0.f};
#pragma unroll
      for (int kt = 0; kt < 2; ++kt) {
        int aoff = (m16 + l15) * 64 + kt * 32 + quad * 8;
        short8 Ah = *(const short8*)(aw1h + aoff);
        short8 Al = *(const short8*)(aw1l + aoff);
        int boff = (nt * 16 + l15) * 72 + kt * 32 + quad * 8;
        short8 Bh = *(const short8*)(sSh + boff);
        short8 Bl = *(const short8*)(sSl + boff);
        acc = __builtin_amdgcn_mfma_f32_16x16x32_bf16(Ah, Bh, acc, 0, 0, 0);
        acc = __builtin_amdgcn_mfma_f32_16x16x32_bf16(Ah, Bl, acc, 0, 0, 0);
        acc = __builtin_amdgcn_mfma_f32_16x16x32_bf16(Al, Bh, acc, 0, 0, 0);
      }
#pragma unroll
      for (int r = 0; r < 4; ++r) {
        int c = m16 + quad * 4 + r;
        float hv = fmaxf((acc[r] + wf[OAB1 + c]) * wf[OASC + c] + wf[OASH + c], 0.f);
        unsigned short hh = f2bf(hv);
        sHh[l15 * 264 + c] = hh;
        sHl[l15 * 264 + c] = f2bf(hv - bf2f(hh));
      }
    }
    __syncthreads();

    // P5: logits[128][16-cols] = wt^T @ h  (split-bf16 MFMA)
#pragma unroll
    for (int mt = 0; mt < 2; ++mt) {
      int m16 = (wave * 2 + mt) * 16;
      f32x4 acc = {0.f, 0.f, 0.f, 0.f};
#pragma unroll 2
      for (int kt = 0; kt < 8; ++kt) {
        int aoff = (m16 + l15) * 256 + kt * 32 + quad * 8;
        short8 Ah = *(const short8*)(wth + aoff);
        short8 Al = *(const short8*)(wtl + aoff);
        int boff = l15 * 264 + kt * 32 + quad * 8;
        short8 Bh = *(const short8*)(sHh + boff);
        short8 Bl = *(const short8*)(sHl + boff);
        acc = __builtin_amdgcn_mfma_f32_16x16x32_bf16(Ah, Bh, acc, 0, 0, 0);
        acc = __builtin_amdgcn_mfma_f32_16x16x32_bf16(Ah, Bl, acc, 0, 0, 0);
        acc = __builtin_amdgcn_mfma_f32_16x16x32_bf16(Al, Bh, acc, 0, 0, 0);
      }
      int kk = nt * 16 + l15;
      if (kk < 20) {
#pragma unroll
        for (int r = 0; r < 4; ++r) lg[kk * 129 + m16 + quad * 4 + r] = acc[r];
      }
    }
    __syncthreads();   // lg complete (nt1) / sH reusable (nt0)
  }

  // P6: softmax over k + aggregate with val
  if (tid < 128) {
    int orr = tid, o = orr >> 1;
    float l[20];
#pragma unroll
    for (int kk = 0; kk < 20; ++kk) l[kk] = lg[kk * 129 + orr];
    float bt = wf[OABT + o];
    float m = -3.4e38f;
#pragma unroll
    for (int kk = 0; kk < 20; ++kk) { l[kk] += bt; m = fmaxf(m, l[kk]); }
    float s = 0.f;
#pragma unroll
    for (int kk = 0; kk < 20; ++kk) { l[kk] = expf(l[kk] - m); s += l[kk]; }
    float inv = 1.f / s;
    float a = 0.f;
#pragma unroll
    for (int kk = 0; kk < 20; ++kk) a += l[kk] * sVal[kk * 65 + o];
    aggs[orr] = a * inv;
  }
  __syncthreads();

  // P7: y = we @ agg + be + iden
  {
    int co = tid & 127, r = tid >> 7;
    float idv = idenb[((size_t)b * N_ + n) * 128 + co];
    float y = wf[OBE + co];
    const float* w = wf + OWET + co;
#pragma unroll 4
    for (int o = 0; o < 64; ++o) y += w[o * 128] * aggs[o * 2 + r];
    out[((size_t)b * 128 + co) * (size_t)(2 * N_) + 2 * n + r] = y + idv;
  }
}

extern "C" void kernel_launch(void* const* d_in, const int* in_sizes, int n_in,
                              void* d_out, int out_size, void* d_ws, size_t ws_size,
                              hipStream_t stream) {
  (void)in_sizes; (void)n_in; (void)out_size; (void)ws_size;
  InPtrs ip;
  for (int i = 0; i < 38; ++i) ip.p[i] = (const float*)d_in[i];
  char* ws = (char*)d_ws;
  float* wf    = (float*)(ws + OFFB_WF);
  int*   idxb  = (int*)(ws + OFFB_IDX);
  float* qb    = (float*)(ws + OFFB_Q);
  float* kb    = (float*)(ws + OFFB_K);
  float* ubuf  = (float*)(ws + OFFB_U);
  float* vbuf  = (float*)(ws + OFFB_V);
  float* idenb = (float*)(ws + OFFB_IDEN);

  k_prep<<<dim3(256), dim3(256), 0, stream>>>(ip, wf);
  k_mv<<<dim3(128, 8), dim3(256), 0, stream>>>(wf, ip.p[1], ip.p[2], vbuf, idenb);
  Gx g{ip.p[2], ip.p[1], ip.p[3], qb, kb, ubuf};
  k_gemm64x3<<<dim3(32, 3, 8), dim3(256), 0, stream>>>(wf, g);
  k_knn<<<dim3(B_ * N_), dim3(256), 0, stream>>>(ip.p[0], idxb);
  k_attn<<<dim3(B_ * N_), dim3(256), 0, stream>>>(wf, qb, kb, vbuf, ubuf, idenb, idxb,
                                                  ip.p[0], (float*)d_out);
}

// Round 8
// 1882.186 us; speedup vs baseline: 1.0978x; 1.0978x over previous
//
#include <hip/hip_runtime.h>
#include <hip/hip_bf16.h>

constexpr int B_ = 8, N_ = 2048, K_ = 20;
constexpr float EPS_ = 1e-5f;

// ---- weight area offsets (in floats) ----
constexpr int OW1T = 0;                    // W1^T  [512][256]
constexpr int OWST = OW1T + 512 * 256;     // Ws^T  [512][256]
constexpr int OW2T = OWST + 512 * 256;     // W2^T  [256][256]
constexpr int OWQT = OW2T + 256 * 256;     // wq^T  [256][64]
constexpr int OWKT = OWQT + 256 * 64;
constexpr int OWVT = OWKT + 256 * 64;
constexpr int OWUT = OWVT + 256 * 64;
constexpr int OWRT = OWUT + 256 * 64;      // wr^T  [256][128]
constexpr int OWET = OWRT + 256 * 128;     // we^T  [o][co] 64x128
constexpr int OWTC = OWET + 64 * 128;      // am_wt [c][o*2+r] 256x128 (native)
constexpr int OAW1 = OWTC + 256 * 128;     // am_w1^T [o(64)][c(256)]
constexpr int OPW1 = OAW1 + 64 * 256;      // pm_w1 [ph][3]
constexpr int OPW2 = OPW1 + 64 * 3;        // pm_w2 [o][c] 64x64 (native)
constexpr int OB1  = OPW2 + 64 * 64;       // mv_b1 [256]
constexpr int OBS2 = OB1 + 256;            // mv_bs + mv_b2 [256]
constexpr int OBQ  = OBS2 + 256;
constexpr int OBK  = OBQ + 64;
constexpr int OBV  = OBK + 64;
constexpr int OBU  = OBV + 64;
constexpr int OBR  = OBU + 64;             // [128]
constexpr int OBE  = OBR + 128;            // [128]
constexpr int OPB1 = OBE + 128;            // [64]
constexpr int OPSC = OPB1 + 64;
constexpr int OPSH = OPSC + 64;
constexpr int OPB2 = OPSH + 64;
constexpr int OASC = OPB2 + 64;            // [256]
constexpr int OASH = OASC + 256;
constexpr int OAB1 = OASH + 256;
constexpr int OABT = OAB1 + 256;           // [64]

// ---- workspace byte offsets (28 MiB total) ----
constexpr size_t OFFB_WF   = 0;
constexpr size_t OFFB_IDX  = (size_t)2 << 20;
constexpr size_t OFFB_Q    = (size_t)4 << 20;   // [b][n][64]
constexpr size_t OFFB_K    = (size_t)8 << 20;   // [b][n][64]
constexpr size_t OFFB_U    = (size_t)12 << 20;  // [b][n][64]
constexpr size_t OFFB_V    = (size_t)16 << 20;  // [b][n][64]
constexpr size_t OFFB_IDEN = (size_t)20 << 20;  // [b][n][128]

struct InPtrs { const float* p[38]; };

// ------------------------------------------------------------------
// Weight prep: transposes + BN folds (all f32)
// ------------------------------------------------------------------
__global__ __launch_bounds__(256) void k_prep(InPtrs in, float* __restrict__ wf) {
  const int tid = blockIdx.x * 256 + threadIdx.x;
  const int nth = gridDim.x * 256;
  const float *mv_w1 = in.p[4], *mv_b1 = in.p[5], *mv_w2 = in.p[6], *mv_b2 = in.p[7],
              *mv_ws = in.p[8], *mv_bs = in.p[9], *wk = in.p[10], *bk = in.p[11],
              *wq = in.p[12], *bq = in.p[13], *wv = in.p[14], *bv = in.p[15],
              *wu = in.p[16], *bu = in.p[17], *pm_w1 = in.p[18], *pm_b1 = in.p[19],
              *pm_g = in.p[20], *pm_be = in.p[21], *pm_m = in.p[22], *pm_v = in.p[23],
              *pm_w2 = in.p[24], *pm_b2 = in.p[25], *am_w1 = in.p[26], *am_b1 = in.p[27],
              *am_g = in.p[28], *am_be = in.p[29], *am_m = in.p[30], *am_v = in.p[31],
              *am_wt = in.p[32], *am_bt = in.p[33], *we = in.p[34], *be = in.p[35],
              *wr = in.p[36], *br = in.p[37];

  for (int i = tid; i < 512 * 256; i += nth) { int c = i >> 8, m = i & 255; wf[OW1T + i] = mv_w1[m * 512 + c]; }
  for (int i = tid; i < 512 * 256; i += nth) { int c = i >> 8, m = i & 255; wf[OWST + i] = mv_ws[m * 512 + c]; }
  for (int i = tid; i < 256 * 256; i += nth) { int c = i >> 8, m = i & 255; wf[OW2T + i] = mv_w2[m * 256 + c]; }
  for (int i = tid; i < 256 * 64; i += nth) { int c = i >> 6, m = i & 63; wf[OWQT + i] = wq[m * 256 + c]; }
  for (int i = tid; i < 256 * 64; i += nth) { int c = i >> 6, m = i & 63; wf[OWKT + i] = wk[m * 256 + c]; }
  for (int i = tid; i < 256 * 64; i += nth) { int c = i >> 6, m = i & 63; wf[OWVT + i] = wv[m * 256 + c]; }
  for (int i = tid; i < 256 * 64; i += nth) { int c = i >> 6, m = i & 63; wf[OWUT + i] = wu[m * 256 + c]; }
  for (int i = tid; i < 256 * 128; i += nth) { int c = i >> 7, m = i & 127; wf[OWRT + i] = wr[m * 256 + c]; }
  for (int i = tid; i < 64 * 128; i += nth) { int o = i >> 7, co = i & 127; wf[OWET + i] = we[co * 64 + o]; }
  for (int i = tid; i < 256 * 128; i += nth) wf[OWTC + i] = am_wt[i];
  for (int i = tid; i < 64 * 256; i += nth) { int o = i >> 8, c = i & 255; wf[OAW1 + i] = am_w1[c * 64 + o]; }
  for (int i = tid; i < 192; i += nth) wf[OPW1 + i] = pm_w1[i];
  for (int i = tid; i < 4096; i += nth) wf[OPW2 + i] = pm_w2[i];
  for (int i = tid; i < 256; i += nth) {
    wf[OB1 + i] = mv_b1[i];
    wf[OBS2 + i] = mv_bs[i] + mv_b2[i];
    float sc = am_g[i] / sqrtf(am_v[i] + EPS_);
    wf[OASC + i] = sc;
    wf[OASH + i] = am_be[i] - am_m[i] * sc;
    wf[OAB1 + i] = am_b1[i];
  }
  for (int i = tid; i < 64; i += nth) {
    wf[OBQ + i] = bq[i]; wf[OBK + i] = bk[i];
    wf[OBV + i] = bv[i]; wf[OBU + i] = bu[i];
    wf[OABT + i] = am_bt[i]; wf[OPB1 + i] = pm_b1[i]; wf[OPB2 + i] = pm_b2[i];
    float sc = pm_g[i] / sqrtf(pm_v[i] + EPS_);
    wf[OPSC + i] = sc;
    wf[OPSH + i] = pm_be[i] - pm_m[i] * sc;
  }
  for (int i = tid; i < 128; i += nth) { wf[OBR + i] = br[i]; wf[OBE + i] = be[i]; }
}

// ------------------------------------------------------------------
// Fused mv-MLP + v/iden projections. Outputs transposed: [b][n][ch].
// ------------------------------------------------------------------
__global__ __launch_bounds__(256) void k_mv(const float* __restrict__ wf,
                                            const float* __restrict__ keyf,
                                            const float* __restrict__ qryf,
                                            float* __restrict__ vout,
                                            float* __restrict__ idenout) {
  const int b = blockIdx.y;
  const int n0 = blockIdx.x * 16;
  __shared__ float hidL[256][16];
  __shared__ float valL[256][16];
  __shared__ float wsL[16][64];
  __shared__ float xsL[16][16];
  const int tid = threadIdx.x;
  const int tn = tid & 15, tm = tid >> 4;

  for (int ms = 0; ms < 4; ++ms) {
    float acc[4] = {};
    for (int kt = 0; kt < 512; kt += 16) {
      for (int i = tid; i < 1024; i += 256) {
        int kk = i >> 6, col = i & 63;
        wsL[kk][col] = wf[OW1T + (size_t)(kt + kk) * 256 + ms * 64 + col];
      }
      {
        int kk = tid >> 4, col = tid & 15;
        int c = kt + kk;
        const float* s = (c < 256) ? keyf : qryf;
        xsL[kk][col] = s[((size_t)b * 256 + (c & 255)) * N_ + n0 + col];
      }
      __syncthreads();
#pragma unroll
      for (int kk = 0; kk < 16; ++kk) {
        float x = xsL[kk][tn];
        float4 w4 = *(const float4*)&wsL[kk][tm * 4];
        acc[0] += w4.x * x; acc[1] += w4.y * x; acc[2] += w4.z * x; acc[3] += w4.w * x;
      }
      __syncthreads();
    }
#pragma unroll
    for (int i = 0; i < 4; ++i)
      hidL[ms * 64 + tm * 4 + i][tn] = fmaxf(acc[i] + wf[OB1 + ms * 64 + tm * 4 + i], 0.f);
  }
  __syncthreads();

  for (int ms = 0; ms < 4; ++ms) {
    float acc[4] = {};
    for (int kt = 0; kt < 512; kt += 16) {
      for (int i = tid; i < 1024; i += 256) {
        int kk = i >> 6, col = i & 63;
        wsL[kk][col] = wf[OWST + (size_t)(kt + kk) * 256 + ms * 64 + col];
      }
      {
        int kk = tid >> 4, col = tid & 15;
        int c = kt + kk;
        const float* s = (c < 256) ? keyf : qryf;
        xsL[kk][col] = s[((size_t)b * 256 + (c & 255)) * N_ + n0 + col];
      }
      __syncthreads();
#pragma unroll
      for (int kk = 0; kk < 16; ++kk) {
        float x = xsL[kk][tn];
        float4 w4 = *(const float4*)&wsL[kk][tm * 4];
        acc[0] += w4.x * x; acc[1] += w4.y * x; acc[2] += w4.z * x; acc[3] += w4.w * x;
      }
      __syncthreads();
    }
    for (int kt = 0; kt < 256; kt += 16) {
      for (int i = tid; i < 1024; i += 256) {
        int kk = i >> 6, col = i & 63;
        wsL[kk][col] = wf[OW2T + (size_t)(kt + kk) * 256 + ms * 64 + col];
      }
      __syncthreads();
#pragma unroll
      for (int kk = 0; kk < 16; ++kk) {
        float x = hidL[kt + kk][tn];
        float4 w4 = *(const float4*)&wsL[kk][tm * 4];
        acc[0] += w4.x * x; acc[1] += w4.y * x; acc[2] += w4.z * x; acc[3] += w4.w * x;
      }
      __syncthreads();
    }
#pragma unroll
    for (int i = 0; i < 4; ++i)
      valL[ms * 64 + tm * 4 + i][tn] = acc[i] + wf[OBS2 + ms * 64 + tm * 4 + i];
  }
  __syncthreads();

  {
    float acc[4] = {};
    for (int kt = 0; kt < 256; kt += 16) {
      for (int i = tid; i < 1024; i += 256) {
        int kk = i >> 6, col = i & 63;
        wsL[kk][col] = wf[OWVT + (size_t)(kt + kk) * 64 + col];
      }
      __syncthreads();
#pragma unroll
      for (int kk = 0; kk < 16; ++kk) {
        float x = valL[kt + kk][tn];
        float4 w4 = *(const float4*)&wsL[kk][tm * 4];
        acc[0] += w4.x * x; acc[1] += w4.y * x; acc[2] += w4.z * x; acc[3] += w4.w * x;
      }
      __syncthreads();
    }
    *(float4*)(vout + ((size_t)b * N_ + n0 + tn) * 64 + tm * 4) =
        make_float4(acc[0] + wf[OBV + tm * 4], acc[1] + wf[OBV + tm * 4 + 1],
                    acc[2] + wf[OBV + tm * 4 + 2], acc[3] + wf[OBV + tm * 4 + 3]);
  }
  for (int ms = 0; ms < 2; ++ms) {
    float acc[4] = {};
    for (int kt = 0; kt < 256; kt += 16) {
      for (int i = tid; i < 1024; i += 256) {
        int kk = i >> 6, col = i & 63;
        wsL[kk][col] = wf[OWRT + (size_t)(kt + kk) * 128 + ms * 64 + col];
      }
      __syncthreads();
#pragma unroll
      for (int kk = 0; kk < 16; ++kk) {
        float x = valL[kt + kk][tn];
        float4 w4 = *(const float4*)&wsL[kk][tm * 4];
        acc[0] += w4.x * x; acc[1] += w4.y * x; acc[2] += w4.z * x; acc[3] += w4.w * x;
      }
      __syncthreads();
    }
    int m = ms * 64 + tm * 4;
    *(float4*)(idenout + ((size_t)b * N_ + n0 + tn) * 128 + m) =
        make_float4(acc[0] + wf[OBR + m], acc[1] + wf[OBR + m + 1],
                    acc[2] + wf[OBR + m + 2], acc[3] + wf[OBR + m + 3]);
  }
}

// ------------------------------------------------------------------
// q/k/u projections, one launch; outputs transposed [b][n][64].
// ------------------------------------------------------------------
struct Gx { const float* x0; const float* x1; const float* x2;
            float* o0; float* o1; float* o2; };

__global__ __launch_bounds__(256) void k_gemm64x3(const float* __restrict__ wf, Gx g) {
  const int b = blockIdx.z;
  const int n0 = blockIdx.x * 64;
  const int y = blockIdx.y;
  const int wsel = (y == 2) ? 3 : y;
  const float* Wt = wf + OWQT + wsel * (256 * 64);
  const float* bias = wf + OBQ + wsel * 64;
  const float* x = (y == 0) ? g.x0 : (y == 1) ? g.x1 : g.x2;
  float* out = (y == 0) ? g.o0 : (y == 1) ? g.o1 : g.o2;
  __shared__ float ws_[16][64];
  __shared__ float xs_[16][64];
  const int tid = threadIdx.x, tm = tid & 15, tn = tid >> 4;
  float acc[4][4] = {};
  for (int kt = 0; kt < 256; kt += 16) {
    for (int i = tid; i < 1024; i += 256) {
      int kk = i >> 6, col = i & 63;
      ws_[kk][col] = Wt[(size_t)(kt + kk) * 64 + col];
      xs_[kk][col] = x[((size_t)b * 256 + kt + kk) * N_ + n0 + col];
    }
    __syncthreads();
#pragma unroll
    for (int kk = 0; kk < 16; ++kk) {
      float4 x4 = *(const float4*)&xs_[kk][tn * 4];
      float4 w4 = *(const float4*)&ws_[kk][tm * 4];
      float wv[4] = {w4.x, w4.y, w4.z, w4.w};
      float xv[4] = {x4.x, x4.y, x4.z, x4.w};
#pragma unroll
      for (int i = 0; i < 4; ++i)
#pragma unroll
        for (int j = 0; j < 4; ++j) acc[i][j] += wv[i] * xv[j];
    }
    __syncthreads();
  }
#pragma unroll
  for (int j = 0; j < 4; ++j) {
    *(float4*)(out + ((size_t)b * N_ + n0 + tn * 4 + j) * 64 + tm * 4) =
        make_float4(acc[0][j] + bias[tm * 4], acc[1][j] + bias[tm * 4 + 1],
                    acc[2][j] + bias[tm * 4 + 2], acc[3][j] + bias[tm * 4 + 3]);
  }
}

// ------------------------------------------------------------------
// Self-KNN, register-resident, 1 barrier per round.
// NOTE: the neighbor-kill uses a statically-unrolled index compare —
// a dynamic d2[mi>>8] write forces d2[] into scratch (HBM) and was
// costing ~850 us/launch.
// ------------------------------------------------------------------
__global__ __launch_bounds__(256, 4) void k_knn(const float* __restrict__ pos,
                                                int* __restrict__ idxout) {
  const int b = blockIdx.x >> 11, n = blockIdx.x & 2047;
  __shared__ double redd[2][4];
  __shared__ int redi[2][4];
  const int tid = threadIdx.x;
  const float* pb = pos + (size_t)b * 3 * N_;
  const double xq = pb[n], yq = pb[N_ + n], zq = pb[2 * N_ + n];
  const double sq = xq * xq + yq * yq + zq * zq;
  double d2[8];
#pragma unroll
  for (int s = 0; s < 8; ++s) {
    int i = tid + s * 256;
    double x = pb[i], y = pb[N_ + i], z = pb[2 * N_ + i];
    double psq = x * x + y * y + z * z;
    double dot = xq * x + yq * y + zq * z;
    d2[s] = (sq + psq) - 2.0 * dot;
  }
  const int lane = tid & 63, wv = tid >> 6;
  for (int r = 0; r < K_; ++r) {
    double bd = d2[0];
    int bi = tid;
#pragma unroll
    for (int s = 1; s < 8; ++s)
      if (d2[s] < bd) { bd = d2[s]; bi = tid + s * 256; }
#pragma unroll
    for (int off = 32; off; off >>= 1) {
      double od = __shfl_down(bd, off);
      int oi = __shfl_down(bi, off);
      if (od < bd || (od == bd && oi < bi)) { bd = od; bi = oi; }
    }
    int ph = r & 1;
    if (lane == 0) { redd[ph][wv] = bd; redi[ph][wv] = bi; }
    __syncthreads();
    double md = redd[ph][0];
    int mi = redi[ph][0];
#pragma unroll
    for (int w = 1; w < 4; ++w)
      if (redd[ph][w] < md || (redd[ph][w] == md && redi[ph][w] < mi)) { md = redd[ph][w]; mi = redi[ph][w]; }
    if (tid == 0) idxout[((size_t)b * N_ + n) * K_ + r] = mi;
    // static-index kill: keeps d2[] in VGPRs (no scratch)
#pragma unroll
    for (int s = 0; s < 8; ++s)
      if (mi == tid + s * 256) d2[s] = __builtin_inf();
  }
}

// ------------------------------------------------------------------
// Fused attention tail v3 (reverted): transposed inputs, conflict-free
// LDS, register-tiled P4/P5. 36.9 KB LDS -> 4 blocks/CU.
// ------------------------------------------------------------------
__global__ __launch_bounds__(256, 4) void k_attn(
    const float* __restrict__ wf,
    const float* __restrict__ qb, const float* __restrict__ kb,
    const float* __restrict__ vb, const float* __restrict__ ub,
    const float* __restrict__ idenb, const int* __restrict__ idxb,
    const float* __restrict__ pos, float* __restrict__ out) {
  const int b = blockIdx.x >> 11, n = blockIdx.x & 2047;
  const int tid = threadIdx.x;
  __shared__ __align__(16) float smem[9216];
  float* sS   = smem;                 // [20][65]
  float* t1s  = smem + 1300;          // [20][64]
  float* lg   = smem;                 // [20][129] overlays sS+t1s
  float* sVal = smem + 2580;          // [20][65]
  float* sHs  = smem + 3880;          // [20][260]
  float* aggs = smem + 9080;          // [128]
  __shared__ int idxs[20];
  __shared__ float prx[20], pry[20], prz[20];

  if (tid < 20) idxs[tid] = idxb[((size_t)b * N_ + n) * K_ + tid] & 2047;
  __syncthreads();

  const int o64 = tid & 63, kslot = tid >> 6, kk0 = kslot * 5;

  // P1: coalesced gathers ([b][n][64] layouts), fold q/u terms
  {
    size_t rowq = ((size_t)b * N_ + n) * 64;
    float qvo = qb[rowq + o64];
    float ufo = ub[rowq + o64];
#pragma unroll
    for (int t = 0; t < 5; ++t) {
      int kk = kk0 + t;
      int j = idxs[kk];
      size_t rowj = ((size_t)b * N_ + j) * 64;
      float kvv = kb[rowj + o64], vvv = vb[rowj + o64], uvv = ub[rowj + o64];
      float ur = ufo - uvv;
      sS[kk * 65 + o64] = (qvo - kvv) + ur;
      sVal[kk * 65 + o64] = vvv + ur;
    }
    if (tid < 20) {
      int j = idxs[tid];
      const float* pp = pos + (size_t)b * 3 * N_;
      prx[tid] = pp[n] - pp[j];
      pry[tid] = pp[N_ + n] - pp[N_ + j];
      prz[tid] = pp[2 * N_ + n] - pp[2 * N_ + j];
    }
  }
  __syncthreads();

  // P2: pos-MLP layer1 + BN + relu -> t1s[kk][ph]
  {
    int ph = o64;
    float w0 = wf[OPW1 + ph * 3], w1 = wf[OPW1 + ph * 3 + 1], w2 = wf[OPW1 + ph * 3 + 2];
    float pb1 = wf[OPB1 + ph], sc = wf[OPSC + ph], sh = wf[OPSH + ph];
#pragma unroll
    for (int t = 0; t < 5; ++t) {
      int kk = kk0 + t;
      float u = pb1 + w0 * prx[kk] + w1 * pry[kk] + w2 * prz[kk];
      t1s[kk * 64 + ph] = fmaxf(u * sc + sh, 0.f);
    }
  }
  __syncthreads();

  // P3: pos-MLP layer2 in registers, fold into s/val
  {
    float pes[5];
    float pb2 = wf[OPB2 + o64];
#pragma unroll
    for (int t = 0; t < 5; ++t) pes[t] = pb2;
    const float* w = wf + OPW2 + o64 * 64;
#pragma unroll 4
    for (int c4 = 0; c4 < 16; ++c4) {
      float4 w4 = *(const float4*)(w + c4 * 4);
#pragma unroll
      for (int t = 0; t < 5; ++t) {
        float4 tv = *(const float4*)(t1s + (kk0 + t) * 64 + c4 * 4);
        pes[t] += w4.x * tv.x + w4.y * tv.y + w4.z * tv.z + w4.w * tv.w;
      }
    }
#pragma unroll
    for (int t = 0; t < 5; ++t) {
      int idx = (kk0 + t) * 65 + o64;
      sS[idx] += pes[t];
      sVal[idx] += pes[t];
    }
  }
  __syncthreads();

  // P4: h = relu(bn(am_w1 @ s + b1)), tiled 4c x 5kk per thread
  {
    const int cg = tid >> 2, kg = tid & 3;
    float acc[4][5];
#pragma unroll
    for (int i = 0; i < 4; ++i)
#pragma unroll
      for (int t = 0; t < 5; ++t) acc[i][t] = 0.f;
    const float* w = wf + OAW1 + cg * 4;
#pragma unroll 4
    for (int o = 0; o < 64; ++o) {
      float4 w4 = *(const float4*)(w + o * 256);
      float wv[4] = {w4.x, w4.y, w4.z, w4.w};
#pragma unroll
      for (int t = 0; t < 5; ++t) {
        float sv = sS[(kg * 5 + t) * 65 + o];
#pragma unroll
        for (int i = 0; i < 4; ++i) acc[i][t] += wv[i] * sv;
      }
    }
#pragma unroll
    for (int t = 0; t < 5; ++t) {
      float hv[4];
#pragma unroll
      for (int i = 0; i < 4; ++i) {
        int c = cg * 4 + i;
        hv[i] = fmaxf((acc[i][t] + wf[OAB1 + c]) * wf[OASC + c] + wf[OASH + c], 0.f);
      }
      *(float4*)(sHs + (kg * 5 + t) * 260 + cg * 4) = make_float4(hv[0], hv[1], hv[2], hv[3]);
    }
  }
  __syncthreads();

  // P5: logits, tiled 2or x 5kk per thread -> lg[kk][129]
  {
    const int og = tid >> 2, kg = tid & 3;
    const int or0 = og * 2;
    float acc0[5], acc1[5];
#pragma unroll
    for (int t = 0; t < 5; ++t) { acc0[t] = 0.f; acc1[t] = 0.f; }
    const float* wt = wf + OWTC + or0;
#pragma unroll 2
    for (int c4 = 0; c4 < 64; ++c4) {
      float4 h4[5];
#pragma unroll
      for (int t = 0; t < 5; ++t)
        h4[t] = *(const float4*)(sHs + (kg * 5 + t) * 260 + c4 * 4);
      float2 wt2[4];
#pragma unroll
      for (int i = 0; i < 4; ++i) wt2[i] = *(const float2*)(wt + (c4 * 4 + i) * 128);
#pragma unroll
      for (int t = 0; t < 5; ++t) {
        acc0[t] += h4[t].x * wt2[0].x + h4[t].y * wt2[1].x + h4[t].z * wt2[2].x + h4[t].w * wt2[3].x;
        acc1[t] += h4[t].x * wt2[0].y + h4[t].y * wt2[1].y + h4[t].z * wt2[2].y + h4[t].w * wt2[3].y;
      }
    }
#pragma unroll
    for (int t = 0; t < 5; ++t) {
      lg[(kg * 5 + t) * 129 + or0] = acc0[t];
      lg[(kg * 5 + t) * 129 + or0 + 1] = acc1[t];
    }
  }
  __syncthreads();

  // P6: softmax over k + aggregate with val
  if (tid < 128) {
    int orr = tid, o = orr >> 1;
    float l[20];
#pragma unroll
    for (int kk = 0; kk < 20; ++kk) l[kk] = lg[kk * 129 + orr];
    float bt = wf[OABT + o];
    float m = -3.4e38f;
#pragma unroll
    for (int kk = 0; kk < 20; ++kk) { l[kk] += bt; m = fmaxf(m, l[kk]); }
    float s = 0.f;
#pragma unroll
    for (int kk = 0; kk < 20; ++kk) { l[kk] = expf(l[kk] - m); s += l[kk]; }
    float inv = 1.f / s;
    float a = 0.f;
#pragma unroll
    for (int kk = 0; kk < 20; ++kk) a += l[kk] * sVal[kk * 65 + o];
    aggs[orr] = a * inv;
  }
  __syncthreads();

  // P7: y = we @ agg + be + iden
  {
    int co = tid & 127, r = tid >> 7;
    float idv = idenb[((size_t)b * N_ + n) * 128 + co];
    float y = wf[OBE + co];
    const float* w = wf + OWET + co;
#pragma unroll 4
    for (int o = 0; o < 64; ++o) y += w[o * 128] * aggs[o * 2 + r];
    out[((size_t)b * 128 + co) * (size_t)(2 * N_) + 2 * n + r] = y + idv;
  }
}

extern "C" void kernel_launch(void* const* d_in, const int* in_sizes, int n_in,
                              void* d_out, int out_size, void* d_ws, size_t ws_size,
                              hipStream_t stream) {
  (void)in_sizes; (void)n_in; (void)out_size; (void)ws_size;
  InPtrs ip;
  for (int i = 0; i < 38; ++i) ip.p[i] = (const float*)d_in[i];
  char* ws = (char*)d_ws;
  float* wf    = (float*)(ws + OFFB_WF);
  int*   idxb  = (int*)(ws + OFFB_IDX);
  float* qb    = (float*)(ws + OFFB_Q);
  float* kb    = (float*)(ws + OFFB_K);
  float* ubuf  = (float*)(ws + OFFB_U);
  float* vbuf  = (float*)(ws + OFFB_V);
  float* idenb = (float*)(ws + OFFB_IDEN);

  k_prep<<<dim3(256), dim3(256), 0, stream>>>(ip, wf);
  k_mv<<<dim3(128, 8), dim3(256), 0, stream>>>(wf, ip.p[1], ip.p[2], vbuf, idenb);
  Gx g{ip.p[2], ip.p[1], ip.p[3], qb, kb, ubuf};
  k_gemm64x3<<<dim3(32, 3, 8), dim3(256), 0, stream>>>(wf, g);
  k_knn<<<dim3(B_ * N_), dim3(256), 0, stream>>>(ip.p[0], idxb);
  k_attn<<<dim3(B_ * N_), dim3(256), 0, stream>>>(wf, qb, kb, vbuf, ubuf, idenb, idxb,
                                                  ip.p[0], (float*)d_out);
}